// Round 4
// baseline (271.140 us; speedup 1.0000x reference)
//
#include <hip/hip_runtime.h>

typedef unsigned short u16;
typedef _Float16 h8 __attribute__((ext_vector_type(8)));
typedef float f32x16 __attribute__((ext_vector_type(16)));

__device__ inline f32x16 zero16() {
    f32x16 v;
#pragma unroll
    for (int i = 0; i < 16; ++i) v[i] = 0.f;
    return v;
}
__device__ inline u16 f2h_bits(float f) {
    _Float16 h = (_Float16)f;
    u16 u;
    __builtin_memcpy(&u, &h, 2);
    return u;
}

// ---------- prep: X f32 [4096][1024] -> Xh f16 ----------
__global__ void __launch_bounds__(256) prep_x(const float* __restrict__ X, u16* __restrict__ Xh) {
    int i = (blockIdx.x * 256 + threadIdx.x) * 8;
    float4 a = *(const float4*)(X + i);
    float4 b = *(const float4*)(X + i + 4);
    u16 t[8] = {f2h_bits(a.x), f2h_bits(a.y), f2h_bits(a.z), f2h_bits(a.w),
                f2h_bits(b.x), f2h_bits(b.y), f2h_bits(b.z), f2h_bits(b.w)};
    *(uint4*)(Xh + i) = *(uint4*)t;
}

// ---------- prep: W f32 [1024][3072] -> Wt f16 [3072][1024] (transpose+narrow) ----------
__global__ void __launch_bounds__(256) prep_w(const float* __restrict__ W, u16* __restrict__ Wt) {
    __shared__ __attribute__((aligned(16))) u16 tile[64][72];  // [k-local][n-local], padded
    int tn0 = blockIdx.x * 64, tk0 = blockIdx.y * 64;
    int tid = threadIdx.x;
#pragma unroll
    for (int i = 0; i < 4; ++i) {
        int e = (i * 256 + tid) * 4;
        int r = e >> 6, c = e & 63;
        float4 v = *(const float4*)(W + (size_t)(tk0 + r) * 3072 + tn0 + c);
        tile[r][c + 0] = f2h_bits(v.x);
        tile[r][c + 1] = f2h_bits(v.y);
        tile[r][c + 2] = f2h_bits(v.z);
        tile[r][c + 3] = f2h_bits(v.w);
    }
    __syncthreads();
#pragma unroll
    for (int i = 0; i < 2; ++i) {
        int e = (i * 256 + tid) * 8;
        int r = e >> 6, c = e & 63;  // r = n-local, c = k-local base
        u16 tmp[8];
#pragma unroll
        for (int j = 0; j < 8; ++j) tmp[j] = tile[c + j][r];
        *(uint4*)(Wt + (size_t)(tn0 + r) * 1024 + tk0 + c) = *(uint4*)tmp;
    }
}

// ---------- QKV GEMM: [4096x1024] x [1024x3072] -> Q,K,Vt (f16) ----------
// Xh row-major [M][K] f16, Wt row-major [N][K] f16 (both k-contiguous)
__global__ void __launch_bounds__(256) qkv_gemm(const u16* __restrict__ Xh, const u16* __restrict__ Wt,
                                                const float* __restrict__ bias, u16* __restrict__ Qp,
                                                u16* __restrict__ Kp, u16* __restrict__ Vtp) {
    __shared__ __attribute__((aligned(16))) u16 As[128 * 40];  // 128 rows x 32k, stride 40
    __shared__ __attribute__((aligned(16))) u16 Bs[128 * 40];
    int m0 = blockIdx.x * 128, n0 = blockIdx.y * 128;
    int tid = threadIdx.x, wave = tid >> 6, lane = tid & 63;
    int lane31 = lane & 31, half = lane >> 5;
    int wm = wave & 1, wn = wave >> 1;

    f32x16 acc00 = zero16(), acc01 = zero16(), acc10 = zero16(), acc11 = zero16();

    for (int k0 = 0; k0 < 1024; k0 += 32) {
        __syncthreads();
#pragma unroll
        for (int i = 0; i < 2; ++i) {
            int e = (i * 256 + tid) * 8;
            int r = e >> 5, c = e & 31;
            *(uint4*)&As[r * 40 + c] = *(const uint4*)(Xh + (size_t)(m0 + r) * 1024 + k0 + c);
            *(uint4*)&Bs[r * 40 + c] = *(const uint4*)(Wt + (size_t)(n0 + r) * 1024 + k0 + c);
        }
        __syncthreads();
#pragma unroll
        for (int kk = 0; kk < 2; ++kk) {
            h8 a0 = *(const h8*)&As[(wm * 64 + lane31) * 40 + kk * 16 + half * 8];
            h8 a1 = *(const h8*)&As[(wm * 64 + 32 + lane31) * 40 + kk * 16 + half * 8];
            h8 b0 = *(const h8*)&Bs[(wn * 64 + lane31) * 40 + kk * 16 + half * 8];
            h8 b1 = *(const h8*)&Bs[(wn * 64 + 32 + lane31) * 40 + kk * 16 + half * 8];
            acc00 = __builtin_amdgcn_mfma_f32_32x32x16_f16(a0, b0, acc00, 0, 0, 0);
            acc01 = __builtin_amdgcn_mfma_f32_32x32x16_f16(a0, b1, acc01, 0, 0, 0);
            acc10 = __builtin_amdgcn_mfma_f32_32x32x16_f16(a1, b0, acc10, 0, 0, 0);
            acc11 = __builtin_amdgcn_mfma_f32_32x32x16_f16(a1, b1, acc11, 0, 0, 0);
        }
    }

    // epilogue: C/D layout col=lane&31, row=(reg&3)+8*(reg>>2)+4*half
#pragma unroll
    for (int mi = 0; mi < 2; ++mi) {
#pragma unroll
        for (int ni = 0; ni < 2; ++ni) {
            const f32x16& acc = mi == 0 ? (ni == 0 ? acc00 : acc01) : (ni == 0 ? acc10 : acc11);
            int n = n0 + wn * 64 + ni * 32 + lane31;
            float bv = bias[n];
#pragma unroll
            for (int r = 0; r < 16; ++r) {
                int row = (r & 3) + 8 * (r >> 2) + 4 * half;
                int m = m0 + wm * 64 + mi * 32 + row;
                int b = m >> 11, t = m & 2047;
                u16 hv = f2h_bits(acc[r] + bv);
                if (n < 1024) {
                    Qp[((size_t)(b * 16 + (n >> 6)) * 2048 + t) * 64 + (n & 63)] = hv;
                } else if (n < 2048) {
                    int n2 = n - 1024;
                    Kp[((size_t)(b * 16 + (n2 >> 6)) * 2048 + t) * 64 + (n2 & 63)] = hv;
                } else {
                    int n2 = n - 2048;
                    Vtp[((size_t)(b * 16 + (n2 >> 6)) * 64 + (n2 & 63)) * 2048 + t] = hv;
                }
            }
        }
    }
}

// ---------- attention: per-(bh, q-tile 128) block; wave = 32 q rows ----------
// Q [BH][T][64], K [BH][T][64], Vt [BH][64][T]  all f16
__global__ void __launch_bounds__(256) attn(const u16* __restrict__ Qp, const u16* __restrict__ Kp,
                                            const u16* __restrict__ Vtp, float* __restrict__ out) {
    __shared__ __attribute__((aligned(16))) u16 P[4][32 * 40];  // per-wave P tile, stride 40
    int bh = blockIdx.y;
    int b = bh >> 4, h = bh & 15;
    int qt = blockIdx.x;
    int tid = threadIdx.x, wave = tid >> 6, lane = tid & 63;
    int lane31 = lane & 31, half = lane >> 5;
    int qbase = qt * 128 + wave * 32;

    // Q fragments (A-operand, stay in registers across whole K loop)
    const u16* q = Qp + ((size_t)bh * 2048 + qbase + lane31) * 64 + half * 8;
    h8 aQ[4];
#pragma unroll
    for (int kk = 0; kk < 4; ++kk) aQ[kk] = *(const h8*)(q + kk * 16);

    f32x16 y0 = zero16(), y1 = zero16();
    u16* Pw = P[wave];
    const u16* Kbh = Kp + (size_t)bh * 2048 * 64;
    const u16* Vbh = Vtp + (size_t)bh * 64 * 2048;
    int nkt = qt * 4 + wave + 1;  // causal: only tiles with kbase <= qbase+31

    for (int kt = 0; kt < nkt; ++kt) {
        int kbase = kt * 32;
        // S = Q * K^T  (B-operand: lane holds K[key=kbase+lane31][hd chunk])
        f32x16 s = zero16();
        const u16* kp = Kbh + (size_t)(kbase + lane31) * 64 + half * 8;
#pragma unroll
        for (int kk = 0; kk < 4; ++kk) {
            h8 bK = *(const h8*)(kp + kk * 16);
            s = __builtin_amdgcn_mfma_f32_32x32x16_f16(aQ[kk], bK, s, 0, 0, 0);
        }
        // scale + causal mask + relu, C-layout -> LDS (A-layout source)
        int kg = kbase + lane31;
#pragma unroll
        for (int r = 0; r < 16; ++r) {
            int row = (r & 3) + 8 * (r >> 2) + 4 * half;
            int qg = qbase + row;
            float v = s[r] * 0.125f;
            v = (kg <= qg && v > 0.f) ? v : 0.f;
            Pw[row * 40 + lane31] = f2h_bits(v);
        }
        __asm__ volatile("s_waitcnt lgkmcnt(0)" ::: "memory");
        // Y += P * V   (A from LDS, B from Vt contiguous)
        const u16* vp = Vbh + (size_t)lane31 * 2048 + kbase + half * 8;
#pragma unroll
        for (int kk = 0; kk < 2; ++kk) {
            h8 aP = *(const h8*)&Pw[lane31 * 40 + kk * 16 + half * 8];
            h8 bV0 = *(const h8*)(vp + kk * 16);
            h8 bV1 = *(const h8*)(vp + 32 * 2048 + kk * 16);
            y0 = __builtin_amdgcn_mfma_f32_32x32x16_f16(aP, bV0, y0, 0, 0, 0);
            y1 = __builtin_amdgcn_mfma_f32_32x32x16_f16(aP, bV1, y1, 0, 0, 0);
        }
        __asm__ volatile("s_waitcnt lgkmcnt(0)" ::: "memory");
    }

    // epilogue: out fp32 [B][T][1024], d = h*64 + ntile*32 + lane31
    float* ob = out + (size_t)b * 2048 * 1024 + h * 64;
#pragma unroll
    for (int r = 0; r < 16; ++r) {
        int row = (r & 3) + 8 * (r >> 2) + 4 * half;
        int t = qbase + row;
        float* o = ob + (size_t)t * 1024;
        o[lane31] = y0[r];
        o[32 + lane31] = y1[r];
    }
}

extern "C" void kernel_launch(void* const* d_in, const int* in_sizes, int n_in,
                              void* d_out, int out_size, void* d_ws, size_t ws_size,
                              hipStream_t stream) {
    const float* X = (const float*)d_in[0];     // [2,2048,1024] f32 (fp16 values widened)
    const float* W = (const float*)d_in[1];     // [1024,3072] f32
    const float* bias = (const float*)d_in[2];  // [3072] f32
    float* out = (float*)d_out;                 // [2,2048,1024] f32

    char* ws = (char*)d_ws;
    u16* Xh = (u16*)ws;                      // 4096*1024*2 = 8388608 B
    u16* Wt = (u16*)(ws + 8388608);          // 3072*1024*2 = 6291456 B
    u16* Qp = (u16*)(ws + 14680064);         // 8388608 B
    u16* Kp = (u16*)(ws + 23068672);         // 8388608 B
    u16* Vtp = (u16*)(ws + 31457280);        // 8388608 B  (total ~38 MB)

    prep_x<<<2048, 256, 0, stream>>>(X, Xh);
    prep_w<<<dim3(48, 16), 256, 0, stream>>>(W, Wt);
    qkv_gemm<<<dim3(32, 24), 256, 0, stream>>>(Xh, Wt, bias, Qp, Kp, Vtp);
    attn<<<dim3(16, 32), 256, 0, stream>>>(Qp, Kp, Vtp, out);
}

// Round 6
// 202.516 us; speedup vs baseline: 1.3389x; 1.3389x over previous
//
#include <hip/hip_runtime.h>

typedef unsigned short u16;
typedef unsigned int u32;
typedef _Float16 h8 __attribute__((ext_vector_type(8)));
typedef __fp16 fp16x2 __attribute__((ext_vector_type(2)));
typedef float f32x16 __attribute__((ext_vector_type(16)));

__device__ inline f32x16 zero16() {
    f32x16 v;
#pragma unroll
    for (int i = 0; i < 16; ++i) v[i] = 0.f;
    return v;
}
__device__ inline u16 f2h_bits(float f) {
    _Float16 h = (_Float16)f;
    u16 u;
    __builtin_memcpy(&u, &h, 2);
    return u;
}
__device__ inline void load_lds16(const u16* g, u16* l) {
    __builtin_amdgcn_global_load_lds((const __attribute__((address_space(1))) u32*)(const void*)g,
                                     (__attribute__((address_space(3))) u32*)(void*)l, 16, 0, 0);
}

// ---------- prep: X f32 [4096][1024] -> Xh f16 ----------
__global__ void __launch_bounds__(256) prep_x(const float* __restrict__ X, u16* __restrict__ Xh) {
    int i = (blockIdx.x * 256 + threadIdx.x) * 8;
    float4 a = *(const float4*)(X + i);
    float4 b = *(const float4*)(X + i + 4);
    u16 t[8] = {f2h_bits(a.x), f2h_bits(a.y), f2h_bits(a.z), f2h_bits(a.w),
                f2h_bits(b.x), f2h_bits(b.y), f2h_bits(b.z), f2h_bits(b.w)};
    *(uint4*)(Xh + i) = *(uint4*)t;
}

// ---------- prep: W f32 [1024][3072] -> Wt f16 [3072][1024] ----------
__global__ void __launch_bounds__(256) prep_w(const float* __restrict__ W, u16* __restrict__ Wt) {
    __shared__ __attribute__((aligned(16))) u16 tile[64][72];
    int tn0 = blockIdx.x * 64, tk0 = blockIdx.y * 64;
    int tid = threadIdx.x;
#pragma unroll
    for (int i = 0; i < 4; ++i) {
        int e = (i * 256 + tid) * 4;
        int r = e >> 6, c = e & 63;
        float4 v = *(const float4*)(W + (size_t)(tk0 + r) * 3072 + tn0 + c);
        tile[r][c + 0] = f2h_bits(v.x);
        tile[r][c + 1] = f2h_bits(v.y);
        tile[r][c + 2] = f2h_bits(v.z);
        tile[r][c + 3] = f2h_bits(v.w);
    }
    __syncthreads();
#pragma unroll
    for (int i = 0; i < 2; ++i) {
        int e = (i * 256 + tid) * 8;
        int r = e >> 6, c = e & 63;
        u16 tmp[8];
#pragma unroll
        for (int j = 0; j < 8; ++j) tmp[j] = tile[c + j][r];
        *(uint4*)(Wt + (size_t)(tn0 + r) * 1024 + tk0 + c) = *(uint4*)tmp;
    }
}

// ---------- QKV GEMM (m97-style staging): Q gets *0.125 folded in ----------
__global__ void __launch_bounds__(256) qkv_gemm(const u16* __restrict__ Xh, const u16* __restrict__ Wt,
                                                const float* __restrict__ bias, u16* __restrict__ Qp,
                                                u16* __restrict__ Kp, u16* __restrict__ Vtp) {
    __shared__ __attribute__((aligned(16))) u16 As[128 * 32];  // unpadded: matches global_load_lds lane order
    __shared__ __attribute__((aligned(16))) u16 Bs[128 * 32];
    int m0 = blockIdx.x * 128, n0 = blockIdx.y * 128;
    int tid = threadIdx.x, wave = tid >> 6, lane = tid & 63;
    int lane31 = lane & 31, half = lane >> 5;
    int wm = wave & 1, wn = wave >> 1;

    f32x16 acc00 = zero16(), acc01 = zero16(), acc10 = zero16(), acc11 = zero16();

    for (int k0 = 0; k0 < 1024; k0 += 32) {
        __syncthreads();
#pragma unroll
        for (int i = 0; i < 2; ++i) {
            int e = (i * 256 + tid) * 8;
            int r = e >> 5, c = e & 31;
            load_lds16(Xh + (size_t)(m0 + r) * 1024 + k0 + c, &As[e]);
            load_lds16(Wt + (size_t)(n0 + r) * 1024 + k0 + c, &Bs[e]);
        }
        __syncthreads();
#pragma unroll
        for (int kk = 0; kk < 2; ++kk) {
            h8 a0 = *(const h8*)&As[(wm * 64 + lane31) * 32 + kk * 16 + half * 8];
            h8 a1 = *(const h8*)&As[(wm * 64 + 32 + lane31) * 32 + kk * 16 + half * 8];
            h8 b0 = *(const h8*)&Bs[(wn * 64 + lane31) * 32 + kk * 16 + half * 8];
            h8 b1 = *(const h8*)&Bs[(wn * 64 + 32 + lane31) * 32 + kk * 16 + half * 8];
            acc00 = __builtin_amdgcn_mfma_f32_32x32x16_f16(a0, b0, acc00, 0, 0, 0);
            acc01 = __builtin_amdgcn_mfma_f32_32x32x16_f16(a0, b1, acc01, 0, 0, 0);
            acc10 = __builtin_amdgcn_mfma_f32_32x32x16_f16(a1, b0, acc10, 0, 0, 0);
            acc11 = __builtin_amdgcn_mfma_f32_32x32x16_f16(a1, b1, acc11, 0, 0, 0);
        }
    }

#pragma unroll
    for (int mi = 0; mi < 2; ++mi) {
#pragma unroll
        for (int ni = 0; ni < 2; ++ni) {
            const f32x16& acc = mi == 0 ? (ni == 0 ? acc00 : acc01) : (ni == 0 ? acc10 : acc11);
            int n = n0 + wn * 64 + ni * 32 + lane31;
            float bv = bias[n];
            float sc = (n < 1024) ? 0.125f : 1.0f;  // fold attention scale into Q
#pragma unroll
            for (int r = 0; r < 16; ++r) {
                int row = (r & 3) + 8 * (r >> 2) + 4 * half;
                int m = m0 + wm * 64 + mi * 32 + row;
                int b = m >> 11, t = m & 2047;
                u16 hv = f2h_bits((acc[r] + bv) * sc);
                if (n < 1024) {
                    Qp[((size_t)(b * 16 + (n >> 6)) * 2048 + t) * 64 + (n & 63)] = hv;
                } else if (n < 2048) {
                    int n2 = n - 1024;
                    Kp[((size_t)(b * 16 + (n2 >> 6)) * 2048 + t) * 64 + (n2 & 63)] = hv;
                } else {
                    int n2 = n - 2048;
                    Vtp[((size_t)(b * 16 + (n2 >> 6)) * 64 + (n2 & 63)) * 2048 + t] = hv;
                }
            }
        }
    }
}

// ---------- attention v2: transposed algebra, LDS-free P transform, balanced split-K ----------
// Q [BH][T][64] (pre-scaled by 1/8), K [BH][T][64], Vt [BH][64][T]  all f16
// Block: 4 waves. Wave (pairIdx, kHalf) handles q-tiles {t, 63-t} (32 rows each),
// k-range half kHalf of each. Reduction across kHalf pairs via LDS.
__global__ void __launch_bounds__(256) attn(const u16* __restrict__ Qp, const u16* __restrict__ Kp,
                                            const u16* __restrict__ Vtp, float* __restrict__ out) {
    __shared__ float4 red[2 * 16 * 64];  // 32 KB: [pairIdx][acc*4+g][lane]
    int bh = blockIdx.y;
    int b = bh >> 4, h = bh & 15;
    int tid = threadIdx.x, wave = tid >> 6, lane = tid & 63;
    int l31 = lane & 31, half = lane >> 5;
    int pairIdx = wave >> 1, kHalf = wave & 1;
    int t = 2 * blockIdx.x + pairIdx;
    int tiles2[2] = {t, 63 - t};

    const u16* Qbh = Qp + (size_t)bh * 2048 * 64;
    const u16* Kbh = Kp + (size_t)bh * 2048 * 64;
    const u16* Vbh = Vtp + (size_t)bh * 64 * 2048;

    f32x16 acc[4];  // [qset*2 + dhalf], Y^T layout: col=q(l31), row=d
#pragma unroll
    for (int a = 0; a < 4; ++a) acc[a] = zero16();

#pragma unroll
    for (int s = 0; s < 2; ++s) {
        int tt = tiles2[s];
        int qset = tt * 32;
        const u16* qp = Qbh + (size_t)(qset + l31) * 64 + half * 8;
        h8 aQ[4];
#pragma unroll
        for (int kk = 0; kk < 4; ++kk) aQ[kk] = *(const h8*)(qp + kk * 16);

        int nkt = tt + 1;
        int mid = (nkt + 1) >> 1;
        int k0 = kHalf ? mid : 0;
        int k1 = kHalf ? nkt : mid;
        f32x16 y0 = acc[2 * s], y1 = acc[2 * s + 1];
        int qg = qset + l31;

        for (int kt = k0; kt < k1; ++kt) {
            int kbase = kt * 32;
            // S^T = K * Q^T : A-operand = K fragments (row = key), B-operand = Q frags
            const u16* kp = Kbh + (size_t)(kbase + l31) * 64 + half * 8;
            f32x16 sT = zero16();
#pragma unroll
            for (int kk = 0; kk < 4; ++kk) {
                h8 aK = *(const h8*)(kp + kk * 16);
                sT = __builtin_amdgcn_mfma_f32_32x32x16_f16(aK, aQ[kk], sT, 0, 0, 0);
            }
            // causal+relu+pack: lane holds P[q=l31+qset][key = kbase + R(j)+{0,1} + 4*half]
            int cbase = qg - kbase - 4 * half;
            u32 p[8];
#pragma unroll
            for (int j = 0; j < 8; ++j) {
                int row0 = ((2 * j) & 3) + 8 * (j >> 1);
                float v0 = (row0 <= cbase) ? fmaxf(sT[2 * j], 0.f) : 0.f;
                float v1 = (row0 + 1 <= cbase) ? fmaxf(sT[2 * j + 1], 0.f) : 0.f;
                fp16x2 pk = __builtin_amdgcn_cvt_pkrtz(v0, v1);
                __builtin_memcpy(&p[j], &pk, 4);
            }
            u32 x[8];
#pragma unroll
            for (int j = 0; j < 8; ++j) x[j] = (u32)__shfl_xor((int)p[j], 32);
            // B-operand frags: lane needs keys (half*8 + j) [frag0: keys 0..15, frag1: 16..31]
            u32 f0[4], f1[4];
            bool hi = (half != 0);
            f0[0] = hi ? x[2] : p[0];
            f0[1] = hi ? x[3] : p[1];
            f0[2] = hi ? p[2] : x[0];
            f0[3] = hi ? p[3] : x[1];
            f1[0] = hi ? x[6] : p[4];
            f1[1] = hi ? x[7] : p[5];
            f1[2] = hi ? p[6] : x[4];
            f1[3] = hi ? p[7] : x[5];
            h8 bP0, bP1;
            __builtin_memcpy(&bP0, f0, 16);
            __builtin_memcpy(&bP1, f1, 16);
            // Y^T += V^T * P^T : A-operand = Vt rows (d = l31 [+32]), k = key
            const u16* vp0 = Vbh + (size_t)l31 * 2048 + kbase + half * 8;
            const u16* vp1 = vp0 + 32 * 2048;
            h8 aV00 = *(const h8*)vp0;
            h8 aV01 = *(const h8*)(vp0 + 16);
            h8 aV10 = *(const h8*)vp1;
            h8 aV11 = *(const h8*)(vp1 + 16);
            y0 = __builtin_amdgcn_mfma_f32_32x32x16_f16(aV00, bP0, y0, 0, 0, 0);
            y0 = __builtin_amdgcn_mfma_f32_32x32x16_f16(aV01, bP1, y0, 0, 0, 0);
            y1 = __builtin_amdgcn_mfma_f32_32x32x16_f16(aV10, bP0, y1, 0, 0, 0);
            y1 = __builtin_amdgcn_mfma_f32_32x32x16_f16(aV11, bP1, y1, 0, 0, 0);
        }
        acc[2 * s] = y0;
        acc[2 * s + 1] = y1;
    }

    // reduce kHalf partners through LDS
    if (kHalf) {
#pragma unroll
        for (int a = 0; a < 4; ++a)
#pragma unroll
            for (int g = 0; g < 4; ++g) {
                float4 v = make_float4(acc[a][4 * g], acc[a][4 * g + 1], acc[a][4 * g + 2], acc[a][4 * g + 3]);
                red[(pairIdx * 16 + a * 4 + g) * 64 + lane] = v;
            }
    }
    __syncthreads();
    if (!kHalf) {
#pragma unroll
        for (int a = 0; a < 4; ++a)
#pragma unroll
            for (int g = 0; g < 4; ++g) {
                float4 v = red[(pairIdx * 16 + a * 4 + g) * 64 + lane];
                acc[a][4 * g] += v.x;
                acc[a][4 * g + 1] += v.y;
                acc[a][4 * g + 2] += v.z;
                acc[a][4 * g + 3] += v.w;
            }
        // epilogue: out[b][q][h*64 + d]; Y^T: lane=q, reg r -> d = (r&3)+8*(r>>2)+4*half
#pragma unroll
        for (int s = 0; s < 2; ++s) {
            int qrow = tiles2[s] * 32 + l31;
            float* orow = out + ((size_t)b * 2048 + qrow) * 1024 + h * 64;
#pragma unroll
            for (int dh = 0; dh < 2; ++dh) {
                const f32x16& y = acc[2 * s + dh];
#pragma unroll
                for (int g = 0; g < 4; ++g) {
                    int d = dh * 32 + 8 * g + 4 * half;
                    float4 v = make_float4(y[4 * g], y[4 * g + 1], y[4 * g + 2], y[4 * g + 3]);
                    *(float4*)(orow + d) = v;
                }
            }
        }
    }
}

extern "C" void kernel_launch(void* const* d_in, const int* in_sizes, int n_in,
                              void* d_out, int out_size, void* d_ws, size_t ws_size,
                              hipStream_t stream) {
    const float* X = (const float*)d_in[0];     // [2,2048,1024] f32 (fp16 values widened)
    const float* W = (const float*)d_in[1];     // [1024,3072] f32
    const float* bias = (const float*)d_in[2];  // [3072] f32
    float* out = (float*)d_out;                 // [2,2048,1024] f32

    char* ws = (char*)d_ws;
    u16* Xh = (u16*)ws;                      // 8388608 B
    u16* Wt = (u16*)(ws + 8388608);          // 6291456 B
    u16* Qp = (u16*)(ws + 14680064);         // 8388608 B
    u16* Kp = (u16*)(ws + 23068672);         // 8388608 B
    u16* Vtp = (u16*)(ws + 31457280);        // 8388608 B

    prep_x<<<2048, 256, 0, stream>>>(X, Xh);
    prep_w<<<dim3(48, 16), 256, 0, stream>>>(W, Wt);
    qkv_gemm<<<dim3(32, 24), 256, 0, stream>>>(Xh, Wt, bias, Qp, Kp, Vtp);
    attn<<<dim3(16, 32), 256, 0, stream>>>(Qp, Kp, Vtp, out);
}